// Round 10
// baseline (508.740 us; speedup 1.0000x reference)
//
#include <hip/hip_runtime.h>

// PQN soft-quantization: x[32768,1024] f32, c[1024,256] f32 -> out[32768,1024] f32
// D=1024, M=8 subspaces of L=128, K=256 codes, logits scaled by 2*ALPHA=20.
//
// R10: occupancy-first redesign. Rounds 1-9 showed achieved HBM BW scales with
// resident waves (4 waves/CU -> 2.2 TB/s, 8 -> 3.4) and the 128-KB dual-layout
// codebook capped us at 1 block/CU. Fix: keep only csB [l][code] in LDS (64 KB);
// the phase-1 [code][l] operand moves to GLOBAL memory (f16, rho-permuted,
// written once by a pre-kernel into d_ws, 512 KB -> L2-resident, ~2MB/XCD).
// 512-thread blocks at the compiler's native 128-VGPR cap, true demand ~110
// (x converted to f16 fragments at load time; no f32 prefetch window), LDS
// 64 KB -> 2 blocks/CU -> 16 waves/CU (vs 4 before).
//
// Per wave-iter (16 samples):
//   phase 1: z^T[256 codes][16 samples] = cs^T . x^T  (A = ws f16 via L2, B = x f16 regs)
//   softmax: lane (n,g) owns 64 codes of sample n; in-lane + xor16 + xor32
//   phase 2: out^T[128 l][16 samples]  = cs . w^T     (A = LDS csB, B = packed w)
// ws rows are rho-PERMUTED (row 32a+16j+4g+r holds code 32a+8g+4j+r) so the
// phase-2 B-fragment is exactly the packed phase-1 accumulators (no shuffles).

#define D_  1024
#define K_  256
#define L_  128

typedef _Float16 f16;
typedef f16 f16x8 __attribute__((ext_vector_type(8)));
typedef f16 f16x4 __attribute__((ext_vector_type(4)));
typedef float f32x4 __attribute__((ext_vector_type(4)));
typedef unsigned int u32;

// pre-kernel: c[(m*128+l)*256 + code] f32 -> ws[m][rho(code)][l] f16 (512 KB)
__global__ __launch_bounds__(128)
void pqn_prep(const float* __restrict__ c, f16* __restrict__ ws) {
    const int b   = blockIdx.x;          // m*256 + code
    const int m   = b >> 8;
    const int cc  = b & 255;
    const int l   = threadIdx.x;         // 0..127
    const int rho = (cc & ~31) | ((cc & 4) << 2) | ((cc & 24) >> 1) | (cc & 3);
    float v = c[(size_t)(m * L_ + l) * K_ + cc];
    ws[((size_t)m * K_ + rho) * L_ + l] = (f16)v;   // 256-B rows, coalesced
}

__global__ __launch_bounds__(512)
void pqn_main(const float* __restrict__ x, const float* __restrict__ c,
              const f16* __restrict__ ws, float* __restrict__ out) {
    __shared__ unsigned char csB[65536];  // [128 l][256 codes] f16, 512-B rows, ^=(l&7)<<4

    const int tid  = threadIdx.x;
    const int m    = blockIdx.x >> 6;    // 8 subspaces x 64 blocks
    const int bm   = blockIdx.x & 63;
    const int lane = tid & 63;
    const int w    = tid >> 6;           // wave 0..7
    const int n    = lane & 15;          // sample column
    const int g    = lane >> 4;          // quarter-wave (k-group)

    // ---- stage csB (64 KB) with all 512 threads ----
    const float* cm = c + (size_t)m * L_ * K_;       // cm[l*256 + k]
    {
        const int R0 = tid >> 6;         // 0..7
        const int f  = tid & 63;         // code quad
        #pragma unroll
        for (int b = 0; b < 8; ++b) {
            int R  = b * 8 + R0;         // 0..63
            int l0 = 2 * R;
            float4 a  = *reinterpret_cast<const float4*>(cm + (size_t)l0 * K_ + 4 * f);
            float4 bb = *reinterpret_cast<const float4*>(cm + (size_t)(l0 + 1) * K_ + 4 * f);
            f16x4 va = {(f16)a.x, (f16)a.y, (f16)a.z, (f16)a.w};
            f16x4 vb = {(f16)bb.x, (f16)bb.y, (f16)bb.z, (f16)bb.w};
            *reinterpret_cast<f16x4*>(csB + l0 * 512       + ((8 * f) ^ ((l0 & 7) << 4))) = va;
            *reinterpret_cast<f16x4*>(csB + (l0 + 1) * 512 + ((8 * f) ^ (((l0 + 1) & 7) << 4))) = vb;
        }
    }
    __syncthreads();

    const f16* wsm = ws + (size_t)m * K_ * L_ + n * L_ + 8 * g;  // lane base (rho rows)

    #pragma unroll 1
    for (int it = 0; it < 4; ++it) {
        const int row0 = bm * 512 + it * 128 + w * 16 + n;

        // ---- x load (iter-top, latency covered by 16-wave TLP) + cvt to f16 ----
        const float* px = x + (size_t)row0 * D_ + m * L_ + 8 * g;
        float ss = 0.f;
        f16x8 bf[4];
        #pragma unroll
        for (int ks = 0; ks < 4; ++ks) {
            float4 lo = *reinterpret_cast<const float4*>(px + 32 * ks);
            float4 hi = *reinterpret_cast<const float4*>(px + 32 * ks + 4);
            ss = fmaf(lo.x, lo.x, ss); ss = fmaf(lo.y, lo.y, ss);
            ss = fmaf(lo.z, lo.z, ss); ss = fmaf(lo.w, lo.w, ss);
            ss = fmaf(hi.x, hi.x, ss); ss = fmaf(hi.y, hi.y, ss);
            ss = fmaf(hi.z, hi.z, ss); ss = fmaf(hi.w, hi.w, ss);
            bf[ks][0] = (f16)lo.x; bf[ks][1] = (f16)lo.y;
            bf[ks][2] = (f16)lo.z; bf[ks][3] = (f16)lo.w;
            bf[ks][4] = (f16)hi.x; bf[ks][5] = (f16)hi.y;
            bf[ks][6] = (f16)hi.z; bf[ks][7] = (f16)hi.w;
        }
        ss += __shfl_xor(ss, 16);
        ss += __shfl_xor(ss, 32);
        const float fac = 20.0f / fmaxf(sqrtf(ss), 1e-12f);

        // ---- phase 1: A-frags streamed from global ws (L2-resident) ----
        f32x4 acc[16];
        const f32x4 fzero = {0.f, 0.f, 0.f, 0.f};
        #pragma unroll
        for (int ct = 0; ct < 16; ++ct) acc[ct] = fzero;
        #pragma unroll
        for (int ks = 0; ks < 4; ++ks) {
            #pragma unroll
            for (int ct = 0; ct < 16; ++ct) {
                f16x8 af = *reinterpret_cast<const f16x8*>(wsm + ct * 16 * L_ + 32 * ks);
                acc[ct] = __builtin_amdgcn_mfma_f32_16x16x32_f16(af, bf[ks], acc[ct], 0, 0, 0);
            }
        }

        // ---- softmax over 256 codes (lane owns 64 of sample n) ----
        float z0 = -3.0e38f, z1 = -3.0e38f, z2 = -3.0e38f, z3 = -3.0e38f;
        #pragma unroll
        for (int ct = 0; ct < 16; ++ct) {
            z0 = fmaxf(z0, acc[ct][0]); z1 = fmaxf(z1, acc[ct][1]);
            z2 = fmaxf(z2, acc[ct][2]); z3 = fmaxf(z3, acc[ct][3]);
        }
        float zm = fmaxf(fmaxf(z0, z1), fmaxf(z2, z3));
        zm = fmaxf(zm, __shfl_xor(zm, 16));
        zm = fmaxf(zm, __shfl_xor(zm, 32));
        const float nfz = -fac * zm;

        float s0 = 0.f, s1 = 0.f, s2 = 0.f, s3 = 0.f;
        #pragma unroll
        for (int ct = 0; ct < 16; ++ct) {
            float p0 = __expf(fmaf(acc[ct][0], fac, nfz));
            float p1 = __expf(fmaf(acc[ct][1], fac, nfz));
            float p2 = __expf(fmaf(acc[ct][2], fac, nfz));
            float p3 = __expf(fmaf(acc[ct][3], fac, nfz));
            acc[ct][0] = p0; acc[ct][1] = p1; acc[ct][2] = p2; acc[ct][3] = p3;
            s0 += p0; s1 += p1; s2 += p2; s3 += p3;
        }
        float S = (s0 + s1) + (s2 + s3);
        S += __shfl_xor(S, 16);
        S += __shfl_xor(S, 32);
        const float invS = 1.0f / S;

        // ---- pack: phase-2 B-fragments = packed phase-1 accumulators verbatim ----
        u32 P[32];
        #pragma unroll
        for (int ct = 0; ct < 16; ++ct) {
            P[2 * ct]     = __builtin_bit_cast(u32,
                __builtin_amdgcn_cvt_pkrtz(acc[ct][0], acc[ct][1]));
            P[2 * ct + 1] = __builtin_bit_cast(u32,
                __builtin_amdgcn_cvt_pkrtz(acc[ct][2], acc[ct][3]));
        }

        // ---- phase 2: out^T[l][n] = cs . w^T (A = LDS csB) ----
        f32x4 acc2[8];
        #pragma unroll
        for (int lt = 0; lt < 8; ++lt) acc2[lt] = fzero;
        #pragma unroll
        for (int ks2 = 0; ks2 < 8; ++ks2) {
            union { f16x8 v; u32 q[4]; } pb;
            pb.q[0] = P[4 * ks2 + 0]; pb.q[1] = P[4 * ks2 + 1];
            pb.q[2] = P[4 * ks2 + 2]; pb.q[3] = P[4 * ks2 + 3];
            #pragma unroll
            for (int lt = 0; lt < 8; ++lt) {
                f16x8 a2 = *reinterpret_cast<const f16x8*>(
                    csB + (lt * 16 + n) * 512 + ((64 * ks2 + 16 * g) ^ ((n & 7) << 4)));
                acc2[lt] = __builtin_amdgcn_mfma_f32_16x16x32_f16(a2, pb.v, acc2[lt], 0, 0, 0);
            }
        }

        // ---- store (R8 pattern: proven lowest WRITE) ----
        float* po = out + (size_t)row0 * D_ + m * L_ + 4 * g;
        #pragma unroll
        for (int lt = 0; lt < 8; ++lt) {
            f32x4 v;
            v[0] = acc2[lt][0] * invS; v[1] = acc2[lt][1] * invS;
            v[2] = acc2[lt][2] * invS; v[3] = acc2[lt][3] * invS;
            *reinterpret_cast<f32x4*>(po + 16 * lt) = v;
        }
    }
}

extern "C" void kernel_launch(void* const* d_in, const int* in_sizes, int n_in,
                              void* d_out, int out_size, void* d_ws, size_t ws_size,
                              hipStream_t stream) {
    const float* x = (const float*)d_in[0];   // [32768, 1024] f32
    const float* c = (const float*)d_in[1];   // [1024, 256]   f32
    float* out = (float*)d_out;               // [32768, 1024] f32
    f16* ws = (f16*)d_ws;                     // 512 KB: [8][256 rho][128] f16
    (void)in_sizes; (void)n_in; (void)out_size; (void)ws_size;

    pqn_prep<<<dim3(2048), dim3(128), 0, stream>>>(c, ws);
    pqn_main<<<dim3(512), dim3(512), 0, stream>>>(x, c, ws, out);
}

// Round 11
// 390.943 us; speedup vs baseline: 1.3013x; 1.3013x over previous
//
#include <hip/hip_runtime.h>

// PQN soft-quantization: x[32768,1024] f32, c[1024,256] f32 -> out[32768,1024] f32
// D=1024, M=8 subspaces of L=128, K=256 codes, logits scaled by 2*ALPHA=20.
//
// R11: 16-waves/CU + no-spill, via flash-style chunked softmax.
// Evidence base: rounds 1-10 show achieved BW scales with resident waves
// (4/CU->2.2 TB/s, 8->3.1, 16->3.4) and every spill config burns 300-700 MB
// of extra HBM. 512-thr blocks are capped at 128 VGPRs, so TRUE demand must
// fit ~100 regs. This kernel processes the 256 codes in 4 chunks of 64 with
// online-max rescaling applied to the OUTPUT accumulator (acc2 is linear in
// the weights, so acc2 *= exp(m_old-m_new) is exact):
//   per chunk: phase1 acc = 16 regs, P = 8 regs, interleaved phase2.
// Peak live ~90 regs (bf 16 + acc2 32 + acc 16 + P 8 + temps).
// csA ([rho(code)][l] f16) lives in d_ws (512 KB, L2-resident; prep kernel).
// csB ([l][code] f16, XOR-swizzled) in 64 KB LDS -> 2 blocks/CU -> 16 waves/CU.
//
// Layout algebra identical to R8 (validated): lane (n,g); phase-1 C gives
// lane codes {chunk*64 + 16ct + 4g + r}; rho row permutation makes the packed
// exp words feed phase-2 B-fragments verbatim (pb = P[4j..4j+3], ks2=2a+j).

#define D_  1024
#define K_  256
#define L_  128

typedef _Float16 f16;
typedef f16 f16x8 __attribute__((ext_vector_type(8)));
typedef f16 f16x4 __attribute__((ext_vector_type(4)));
typedef float f32x4 __attribute__((ext_vector_type(4)));
typedef unsigned int u32;

// prep: c[(m*128+l)*256 + code] f32 -> ws[m][rho(code)][l] f16 (512 KB)
__global__ __launch_bounds__(128)
void pqn_prep(const float* __restrict__ c, f16* __restrict__ ws) {
    const int b   = blockIdx.x;          // m*256 + code
    const int m   = b >> 8;
    const int cc  = b & 255;
    const int l   = threadIdx.x;         // 0..127
    const int rho = (cc & ~31) | ((cc & 4) << 2) | ((cc & 24) >> 1) | (cc & 3);
    float v = c[(size_t)(m * L_ + l) * K_ + cc];
    ws[((size_t)m * K_ + rho) * L_ + l] = (f16)v;   // 256-B rows, coalesced
}

__global__ __launch_bounds__(512)
void pqn_main(const float* __restrict__ x, const float* __restrict__ c,
              const f16* __restrict__ ws, float* __restrict__ out) {
    __shared__ unsigned char csB[65536];  // [128 l][256 codes] f16, 512-B rows, ^=(l&7)<<4

    const int tid  = threadIdx.x;
    const int m    = blockIdx.x >> 6;    // 8 subspaces x 64 blocks
    const int bm   = blockIdx.x & 63;
    const int lane = tid & 63;
    const int w    = tid >> 6;           // wave 0..7
    const int n    = lane & 15;          // sample column
    const int g    = lane >> 4;          // quarter-wave (k-group)

    // ---- stage csB (64 KB) with all 512 threads ----
    const float* cm = c + (size_t)m * L_ * K_;       // cm[l*256 + k]
    {
        const int R0 = tid >> 6;         // 0..7
        const int f  = tid & 63;         // code quad
        #pragma unroll
        for (int b = 0; b < 8; ++b) {
            int R  = b * 8 + R0;         // 0..63
            int l0 = 2 * R;
            float4 a  = *reinterpret_cast<const float4*>(cm + (size_t)l0 * K_ + 4 * f);
            float4 bb = *reinterpret_cast<const float4*>(cm + (size_t)(l0 + 1) * K_ + 4 * f);
            f16x4 va = {(f16)a.x, (f16)a.y, (f16)a.z, (f16)a.w};
            f16x4 vb = {(f16)bb.x, (f16)bb.y, (f16)bb.z, (f16)bb.w};
            *reinterpret_cast<f16x4*>(csB + l0 * 512       + ((8 * f) ^ ((l0 & 7) << 4))) = va;
            *reinterpret_cast<f16x4*>(csB + (l0 + 1) * 512 + ((8 * f) ^ (((l0 + 1) & 7) << 4))) = vb;
        }
    }
    __syncthreads();

    const f16* wsm = ws + (size_t)m * (K_ * L_) + (size_t)n * L_ + 8 * g;

    #pragma unroll 1
    for (int it = 0; it < 4; ++it) {
        const int row0 = bm * 512 + it * 128 + w * 16 + n;

        // ---- x load (iter-top; 16-wave TLP covers latency) + cvt to f16 ----
        const float* px = x + (size_t)row0 * D_ + m * L_ + 8 * g;
        float ss = 0.f;
        f16x8 bf[4];
        #pragma unroll
        for (int ks = 0; ks < 4; ++ks) {
            float4 lo = *reinterpret_cast<const float4*>(px + 32 * ks);
            float4 hi = *reinterpret_cast<const float4*>(px + 32 * ks + 4);
            ss = fmaf(lo.x, lo.x, ss); ss = fmaf(lo.y, lo.y, ss);
            ss = fmaf(lo.z, lo.z, ss); ss = fmaf(lo.w, lo.w, ss);
            ss = fmaf(hi.x, hi.x, ss); ss = fmaf(hi.y, hi.y, ss);
            ss = fmaf(hi.z, hi.z, ss); ss = fmaf(hi.w, hi.w, ss);
            bf[ks][0] = (f16)lo.x; bf[ks][1] = (f16)lo.y;
            bf[ks][2] = (f16)lo.z; bf[ks][3] = (f16)lo.w;
            bf[ks][4] = (f16)hi.x; bf[ks][5] = (f16)hi.y;
            bf[ks][6] = (f16)hi.z; bf[ks][7] = (f16)hi.w;
        }
        ss += __shfl_xor(ss, 16);
        ss += __shfl_xor(ss, 32);
        const float fac = 20.0f / fmaxf(sqrtf(ss), 1e-12f);

        // ---- online-softmax fused phase1 -> phase2 over 4 chunks of 64 codes ----
        f32x4 acc2[8];
        const f32x4 fzero = {0.f, 0.f, 0.f, 0.f};
        #pragma unroll
        for (int lt = 0; lt < 8; ++lt) acc2[lt] = fzero;
        float mrun = -3.0e38f;
        float sp   = 0.f;                 // per-lane partial sum (column-consistent m)

        #pragma unroll
        for (int a = 0; a < 4; ++a) {
            // phase-1 chunk: z over codes [64a, 64a+64)
            f32x4 acc[4];
            #pragma unroll
            for (int ct = 0; ct < 4; ++ct) acc[ct] = fzero;
            #pragma unroll
            for (int ks = 0; ks < 4; ++ks) {
                #pragma unroll
                for (int ct = 0; ct < 4; ++ct) {
                    f16x8 af = *reinterpret_cast<const f16x8*>(
                        wsm + (a * 64 + ct * 16) * L_ + 32 * ks);
                    acc[ct] = __builtin_amdgcn_mfma_f32_16x16x32_f16(af, bf[ks], acc[ct], 0, 0, 0);
                }
            }
            // scale to logits, chunk max (column-wide via g-lane reduce)
            float cmax = -3.0e38f;
            #pragma unroll
            for (int ct = 0; ct < 4; ++ct) {
                acc[ct][0] *= fac; acc[ct][1] *= fac;
                acc[ct][2] *= fac; acc[ct][3] *= fac;
                cmax = fmaxf(cmax, fmaxf(fmaxf(acc[ct][0], acc[ct][1]),
                                         fmaxf(acc[ct][2], acc[ct][3])));
            }
            cmax = fmaxf(cmax, __shfl_xor(cmax, 16));
            cmax = fmaxf(cmax, __shfl_xor(cmax, 32));
            const float mnew = fmaxf(mrun, cmax);
            const float r = __expf(mrun - mnew);   // 0 on first chunk, often 1 later
            mrun = mnew;
            sp *= r;
            #pragma unroll
            for (int lt = 0; lt < 8; ++lt) {
                acc2[lt][0] *= r; acc2[lt][1] *= r;
                acc2[lt][2] *= r; acc2[lt][3] *= r;
            }
            // exp + per-lane sum + pack to f16 pairs (p = exp(z - mrun) in (0,1])
            u32 P[8];
            #pragma unroll
            for (int ct = 0; ct < 4; ++ct) {
                float p0 = __expf(acc[ct][0] - mrun);
                float p1 = __expf(acc[ct][1] - mrun);
                float p2 = __expf(acc[ct][2] - mrun);
                float p3 = __expf(acc[ct][3] - mrun);
                sp += (p0 + p1) + (p2 + p3);
                P[2 * ct]     = __builtin_bit_cast(u32, __builtin_amdgcn_cvt_pkrtz(p0, p1));
                P[2 * ct + 1] = __builtin_bit_cast(u32, __builtin_amdgcn_cvt_pkrtz(p2, p3));
            }
            // phase-2 chunk: acc2 += csB[:, chunk] . p_chunk
            #pragma unroll
            for (int j = 0; j < 2; ++j) {
                union { f16x8 v; u32 q[4]; } pb;
                pb.q[0] = P[4 * j + 0]; pb.q[1] = P[4 * j + 1];
                pb.q[2] = P[4 * j + 2]; pb.q[3] = P[4 * j + 3];
                const int ks2 = 2 * a + j;
                #pragma unroll
                for (int lt = 0; lt < 8; ++lt) {
                    f16x8 a2 = *reinterpret_cast<const f16x8*>(
                        csB + (lt * 16 + n) * 512 + ((64 * ks2 + 16 * g) ^ ((n & 7) << 4)));
                    acc2[lt] = __builtin_amdgcn_mfma_f32_16x16x32_f16(a2, pb.v, acc2[lt], 0, 0, 0);
                }
            }
        }

        // ---- final sum reduce + normalized store (R8 pattern) ----
        sp += __shfl_xor(sp, 16);
        sp += __shfl_xor(sp, 32);
        const float invS = 1.0f / sp;

        float* po = out + (size_t)row0 * D_ + m * L_ + 4 * g;
        #pragma unroll
        for (int lt = 0; lt < 8; ++lt) {
            f32x4 v;
            v[0] = acc2[lt][0] * invS; v[1] = acc2[lt][1] * invS;
            v[2] = acc2[lt][2] * invS; v[3] = acc2[lt][3] * invS;
            *reinterpret_cast<f32x4*>(po + 16 * lt) = v;
        }
    }
}

extern "C" void kernel_launch(void* const* d_in, const int* in_sizes, int n_in,
                              void* d_out, int out_size, void* d_ws, size_t ws_size,
                              hipStream_t stream) {
    const float* x = (const float*)d_in[0];   // [32768, 1024] f32
    const float* c = (const float*)d_in[1];   // [1024, 256]   f32
    float* out = (float*)d_out;               // [32768, 1024] f32
    f16* ws = (f16*)d_ws;                     // 512 KB: [8][256 rho][128] f16
    (void)in_sizes; (void)n_in; (void)out_size; (void)ws_size;

    pqn_prep<<<dim3(2048), dim3(128), 0, stream>>>(c, ws);
    pqn_main<<<dim3(512), dim3(512), 0, stream>>>(x, c, ws, out);
}

// Round 12
// 158.992 us; speedup vs baseline: 3.1998x; 2.4589x over previous
//
#include <hip/hip_runtime.h>

// PQN soft-quantization: x[32768,1024] f32, c[1024,256] f32 -> out[32768,1024] f32
// D=1024, M=8 subspaces of L=128, K=256 codes, logits scaled by 2*ALPHA=20.
//
// R12 = R11 (flash-chunked softmax, csA in d_ws via L2, csB in 64 KB LDS,
// 512 thr, 2 blocks/CU target) + SCHEDULE PINNING to actually fit 128 VGPRs:
//   - chunk loop is #pragma unroll 1 (scheduler can't hoist all 64 ws loads)
//   - sched_barrier(0) after each phase-1 ks-group (<=16 frag regs in flight)
//     and after each phase-2 half (<=32 frag regs in flight)
// R2/R4/R5/R6/R10/R11 all spilled not because the live set was >128 but
// because full unrolling let the scheduler keep 64-256 regs of loads in
// flight. Occupancy fallout: scratch also evicted the 2nd block/CU (21.5%
// measured vs 50% theoretical in R11).
//
// Per wave-iter (16 samples), per chunk a (64 codes):
//   phase 1: acc[4] += ws[rho rows 64a..][l] . x^T      (A from global/L2)
//   online softmax: chunk max -> rescale acc2/sp by exp(m_old-m_new)
//   phase 2: acc2[8] += csB[:, 64a..] . p_chunk         (A from LDS)
// rho row-permutation makes packed exp words feed phase-2 B verbatim.

#define D_  1024
#define K_  256
#define L_  128

typedef _Float16 f16;
typedef f16 f16x8 __attribute__((ext_vector_type(8)));
typedef f16 f16x4 __attribute__((ext_vector_type(4)));
typedef float f32x4 __attribute__((ext_vector_type(4)));
typedef unsigned int u32;

// prep: c[(m*128+l)*256 + code] f32 -> ws[m][rho(code)][l] f16 (512 KB)
__global__ __launch_bounds__(128)
void pqn_prep(const float* __restrict__ c, f16* __restrict__ ws) {
    const int b   = blockIdx.x;          // m*256 + code
    const int m   = b >> 8;
    const int cc  = b & 255;
    const int l   = threadIdx.x;         // 0..127
    const int rho = (cc & ~31) | ((cc & 4) << 2) | ((cc & 24) >> 1) | (cc & 3);
    float v = c[(size_t)(m * L_ + l) * K_ + cc];
    ws[((size_t)m * K_ + rho) * L_ + l] = (f16)v;   // 256-B rows, coalesced
}

__global__ __launch_bounds__(512)
void pqn_main(const float* __restrict__ x, const float* __restrict__ c,
              const f16* __restrict__ ws, float* __restrict__ out) {
    __shared__ unsigned char csB[65536];  // [128 l][256 codes] f16, 512-B rows, ^=(l&7)<<4

    const int tid  = threadIdx.x;
    const int m    = blockIdx.x >> 6;    // 8 subspaces x 64 blocks
    const int bm   = blockIdx.x & 63;
    const int lane = tid & 63;
    const int w    = tid >> 6;           // wave 0..7
    const int n    = lane & 15;          // sample column
    const int g    = lane >> 4;          // quarter-wave (k-group)

    // ---- stage csB (64 KB) with all 512 threads ----
    const float* cm = c + (size_t)m * L_ * K_;       // cm[l*256 + k]
    {
        const int R0 = tid >> 6;         // 0..7
        const int f  = tid & 63;         // code quad
        #pragma unroll
        for (int b = 0; b < 8; ++b) {
            int R  = b * 8 + R0;         // 0..63
            int l0 = 2 * R;
            float4 a  = *reinterpret_cast<const float4*>(cm + (size_t)l0 * K_ + 4 * f);
            float4 bb = *reinterpret_cast<const float4*>(cm + (size_t)(l0 + 1) * K_ + 4 * f);
            f16x4 va = {(f16)a.x, (f16)a.y, (f16)a.z, (f16)a.w};
            f16x4 vb = {(f16)bb.x, (f16)bb.y, (f16)bb.z, (f16)bb.w};
            *reinterpret_cast<f16x4*>(csB + l0 * 512       + ((8 * f) ^ ((l0 & 7) << 4))) = va;
            *reinterpret_cast<f16x4*>(csB + (l0 + 1) * 512 + ((8 * f) ^ (((l0 + 1) & 7) << 4))) = vb;
        }
    }
    __syncthreads();

    const f16* wsm = ws + (size_t)m * (K_ * L_) + (size_t)n * L_ + 8 * g;

    #pragma unroll 1
    for (int it = 0; it < 4; ++it) {
        const int row0 = bm * 512 + it * 128 + w * 16 + n;

        // ---- x load + cvt to f16 fragments + row norm ----
        const float* px = x + (size_t)row0 * D_ + m * L_ + 8 * g;
        float ss = 0.f;
        f16x8 bf[4];
        #pragma unroll
        for (int ks = 0; ks < 4; ++ks) {
            float4 lo = *reinterpret_cast<const float4*>(px + 32 * ks);
            float4 hi = *reinterpret_cast<const float4*>(px + 32 * ks + 4);
            ss = fmaf(lo.x, lo.x, ss); ss = fmaf(lo.y, lo.y, ss);
            ss = fmaf(lo.z, lo.z, ss); ss = fmaf(lo.w, lo.w, ss);
            ss = fmaf(hi.x, hi.x, ss); ss = fmaf(hi.y, hi.y, ss);
            ss = fmaf(hi.z, hi.z, ss); ss = fmaf(hi.w, hi.w, ss);
            bf[ks][0] = (f16)lo.x; bf[ks][1] = (f16)lo.y;
            bf[ks][2] = (f16)lo.z; bf[ks][3] = (f16)lo.w;
            bf[ks][4] = (f16)hi.x; bf[ks][5] = (f16)hi.y;
            bf[ks][6] = (f16)hi.z; bf[ks][7] = (f16)hi.w;
        }
        ss += __shfl_xor(ss, 16);
        ss += __shfl_xor(ss, 32);
        const float fac = 20.0f / fmaxf(sqrtf(ss), 1e-12f);

        // ---- online-softmax fused phase1 -> phase2, 4 chunks of 64 codes ----
        f32x4 acc2[8];
        const f32x4 fzero = {0.f, 0.f, 0.f, 0.f};
        #pragma unroll
        for (int lt = 0; lt < 8; ++lt) acc2[lt] = fzero;
        float mrun = -3.0e38f;
        float sp   = 0.f;

        #pragma unroll 1
        for (int a = 0; a < 4; ++a) {
            // phase-1 chunk: z over codes [64a, 64a+64)
            f32x4 acc[4];
            #pragma unroll
            for (int ct = 0; ct < 4; ++ct) acc[ct] = fzero;
            #pragma unroll
            for (int ks = 0; ks < 4; ++ks) {
                #pragma unroll
                for (int ct = 0; ct < 4; ++ct) {
                    f16x8 af = *reinterpret_cast<const f16x8*>(
                        wsm + (a * 64 + ct * 16) * L_ + 32 * ks);
                    acc[ct] = __builtin_amdgcn_mfma_f32_16x16x32_f16(af, bf[ks], acc[ct], 0, 0, 0);
                }
                __builtin_amdgcn_sched_barrier(0);   // cap in-flight ws frags at 16 regs
            }
            // logits + chunk max (column-wide)
            float cmax = -3.0e38f;
            #pragma unroll
            for (int ct = 0; ct < 4; ++ct) {
                acc[ct][0] *= fac; acc[ct][1] *= fac;
                acc[ct][2] *= fac; acc[ct][3] *= fac;
                cmax = fmaxf(cmax, fmaxf(fmaxf(acc[ct][0], acc[ct][1]),
                                         fmaxf(acc[ct][2], acc[ct][3])));
            }
            cmax = fmaxf(cmax, __shfl_xor(cmax, 16));
            cmax = fmaxf(cmax, __shfl_xor(cmax, 32));
            const float mnew = fmaxf(mrun, cmax);
            const float r = __expf(mrun - mnew);
            mrun = mnew;
            sp *= r;
            #pragma unroll
            for (int lt = 0; lt < 8; ++lt) {
                acc2[lt][0] *= r; acc2[lt][1] *= r;
                acc2[lt][2] *= r; acc2[lt][3] *= r;
            }
            // exp + per-lane sum + pack
            u32 P[8];
            #pragma unroll
            for (int ct = 0; ct < 4; ++ct) {
                float p0 = __expf(acc[ct][0] - mrun);
                float p1 = __expf(acc[ct][1] - mrun);
                float p2 = __expf(acc[ct][2] - mrun);
                float p3 = __expf(acc[ct][3] - mrun);
                sp += (p0 + p1) + (p2 + p3);
                P[2 * ct]     = __builtin_bit_cast(u32, __builtin_amdgcn_cvt_pkrtz(p0, p1));
                P[2 * ct + 1] = __builtin_bit_cast(u32, __builtin_amdgcn_cvt_pkrtz(p2, p3));
            }
            __builtin_amdgcn_sched_barrier(0);
            // phase-2 chunk: acc2 += csB[:, chunk] . p_chunk
            #pragma unroll
            for (int j = 0; j < 2; ++j) {
                union { f16x8 v; u32 q[4]; } pb;
                pb.q[0] = P[4 * j + 0]; pb.q[1] = P[4 * j + 1];
                pb.q[2] = P[4 * j + 2]; pb.q[3] = P[4 * j + 3];
                const int ks2 = 2 * a + j;
                #pragma unroll
                for (int lt = 0; lt < 8; ++lt) {
                    f16x8 a2 = *reinterpret_cast<const f16x8*>(
                        csB + (lt * 16 + n) * 512 + ((64 * ks2 + 16 * g) ^ ((n & 7) << 4)));
                    acc2[lt] = __builtin_amdgcn_mfma_f32_16x16x32_f16(a2, pb.v, acc2[lt], 0, 0, 0);
                }
                __builtin_amdgcn_sched_barrier(0);   // cap in-flight csB frags at 32 regs
            }
        }

        // ---- final sum reduce + normalized store ----
        sp += __shfl_xor(sp, 16);
        sp += __shfl_xor(sp, 32);
        const float invS = 1.0f / sp;

        float* po = out + (size_t)row0 * D_ + m * L_ + 4 * g;
        #pragma unroll
        for (int lt = 0; lt < 8; ++lt) {
            f32x4 v;
            v[0] = acc2[lt][0] * invS; v[1] = acc2[lt][1] * invS;
            v[2] = acc2[lt][2] * invS; v[3] = acc2[lt][3] * invS;
            *reinterpret_cast<f32x4*>(po + 16 * lt) = v;
        }
    }
}

extern "C" void kernel_launch(void* const* d_in, const int* in_sizes, int n_in,
                              void* d_out, int out_size, void* d_ws, size_t ws_size,
                              hipStream_t stream) {
    const float* x = (const float*)d_in[0];   // [32768, 1024] f32
    const float* c = (const float*)d_in[1];   // [1024, 256]   f32
    float* out = (float*)d_out;               // [32768, 1024] f32
    f16* ws = (f16*)d_ws;                     // 512 KB: [8][256 rho][128] f16
    (void)in_sizes; (void)n_in; (void)out_size; (void)ws_size;

    pqn_prep<<<dim3(2048), dim3(128), 0, stream>>>(c, ws);
    pqn_main<<<dim3(512), dim3(512), 0, stream>>>(x, c, ws, out);
}

// Round 13
// 156.220 us; speedup vs baseline: 3.2566x; 1.0177x over previous
//
#include <hip/hip_runtime.h>

// PQN soft-quantization: x[32768,1024] f32, c[1024,256] f32 -> out[32768,1024] f32
// D=1024, M=8 subspaces of L=128, K=256 codes, logits scaled by 2*ALPHA=20.
//
// R13 = R12 (flash-chunked softmax, csA in d_ws via L2, csB in 64 KB LDS,
// 512 thr, 2 blocks/CU, sched_barrier-pinned registers: 52 VGPR, no spill,
// 159 us) + ks-granular SOFTWARE PIPELINE in phase 1:
//   region ks = { issue 4 ws loads for ks+1 (double-buffered afA/afB),
//                 4 MFMAs consuming ks }  -- one sched_barrier(0) per region.
// The compiler then emits counted vmcnt waits (never 0): loads stay in
// flight under MFMAs instead of R12's serial 16 L2-latencies per chunk.
// The ks3 slot issues the NEXT chunk's ks0 loads (ws frags are it-invariant,
// so the a=3 -> a=0 wrap is always a valid prefetch for the next iter).
// In-flight frag regs capped at 32 (2 buffers); VGPR ~85-115 < 128 cap.

#define D_  1024
#define K_  256
#define L_  128

typedef _Float16 f16;
typedef f16 f16x8 __attribute__((ext_vector_type(8)));
typedef f16 f16x4 __attribute__((ext_vector_type(4)));
typedef float f32x4 __attribute__((ext_vector_type(4)));
typedef unsigned int u32;

// prep: c[(m*128+l)*256 + code] f32 -> ws[m][rho(code)][l] f16 (512 KB)
__global__ __launch_bounds__(128)
void pqn_prep(const float* __restrict__ c, f16* __restrict__ ws) {
    const int b   = blockIdx.x;          // m*256 + code
    const int m   = b >> 8;
    const int cc  = b & 255;
    const int l   = threadIdx.x;         // 0..127
    const int rho = (cc & ~31) | ((cc & 4) << 2) | ((cc & 24) >> 1) | (cc & 3);
    float v = c[(size_t)(m * L_ + l) * K_ + cc];
    ws[((size_t)m * K_ + rho) * L_ + l] = (f16)v;   // 256-B rows, coalesced
}

__global__ __launch_bounds__(512)
void pqn_main(const float* __restrict__ x, const float* __restrict__ c,
              const f16* __restrict__ ws, float* __restrict__ out) {
    __shared__ unsigned char csB[65536];  // [128 l][256 codes] f16, 512-B rows, ^=(l&7)<<4

    const int tid  = threadIdx.x;
    const int m    = blockIdx.x >> 6;    // 8 subspaces x 64 blocks
    const int bm   = blockIdx.x & 63;
    const int lane = tid & 63;
    const int w    = tid >> 6;           // wave 0..7
    const int n    = lane & 15;          // sample column
    const int g    = lane >> 4;          // quarter-wave (k-group)

    // ---- stage csB (64 KB) with all 512 threads ----
    const float* cm = c + (size_t)m * L_ * K_;       // cm[l*256 + k]
    {
        const int R0 = tid >> 6;         // 0..7
        const int f  = tid & 63;         // code quad
        #pragma unroll
        for (int b = 0; b < 8; ++b) {
            int R  = b * 8 + R0;         // 0..63
            int l0 = 2 * R;
            float4 a  = *reinterpret_cast<const float4*>(cm + (size_t)l0 * K_ + 4 * f);
            float4 bb = *reinterpret_cast<const float4*>(cm + (size_t)(l0 + 1) * K_ + 4 * f);
            f16x4 va = {(f16)a.x, (f16)a.y, (f16)a.z, (f16)a.w};
            f16x4 vb = {(f16)bb.x, (f16)bb.y, (f16)bb.z, (f16)bb.w};
            *reinterpret_cast<f16x4*>(csB + l0 * 512       + ((8 * f) ^ ((l0 & 7) << 4))) = va;
            *reinterpret_cast<f16x4*>(csB + (l0 + 1) * 512 + ((8 * f) ^ (((l0 + 1) & 7) << 4))) = vb;
        }
    }
    __syncthreads();

    const f16* wsm = ws + (size_t)m * (K_ * L_) + (size_t)n * L_ + 8 * g;

    // ---- prime the pipeline: afA <- chunk0 ks0 (it-invariant address) ----
    f16x8 afA[4], afB[4];
    #pragma unroll
    for (int ct = 0; ct < 4; ++ct)
        afA[ct] = *reinterpret_cast<const f16x8*>(wsm + (ct * 16) * L_);

    #pragma unroll 1
    for (int it = 0; it < 4; ++it) {
        const int row0 = bm * 512 + it * 128 + w * 16 + n;

        // ---- x load + cvt to f16 fragments + row norm ----
        const float* px = x + (size_t)row0 * D_ + m * L_ + 8 * g;
        float ss = 0.f;
        f16x8 bf[4];
        #pragma unroll
        for (int ks = 0; ks < 4; ++ks) {
            float4 lo = *reinterpret_cast<const float4*>(px + 32 * ks);
            float4 hi = *reinterpret_cast<const float4*>(px + 32 * ks + 4);
            ss = fmaf(lo.x, lo.x, ss); ss = fmaf(lo.y, lo.y, ss);
            ss = fmaf(lo.z, lo.z, ss); ss = fmaf(lo.w, lo.w, ss);
            ss = fmaf(hi.x, hi.x, ss); ss = fmaf(hi.y, hi.y, ss);
            ss = fmaf(hi.z, hi.z, ss); ss = fmaf(hi.w, hi.w, ss);
            bf[ks][0] = (f16)lo.x; bf[ks][1] = (f16)lo.y;
            bf[ks][2] = (f16)lo.z; bf[ks][3] = (f16)lo.w;
            bf[ks][4] = (f16)hi.x; bf[ks][5] = (f16)hi.y;
            bf[ks][6] = (f16)hi.z; bf[ks][7] = (f16)hi.w;
        }
        ss += __shfl_xor(ss, 16);
        ss += __shfl_xor(ss, 32);
        const float fac = 20.0f / fmaxf(sqrtf(ss), 1e-12f);

        // ---- online-softmax fused phase1 -> phase2, 4 chunks of 64 codes ----
        f32x4 acc2[8];
        const f32x4 fzero = {0.f, 0.f, 0.f, 0.f};
        #pragma unroll
        for (int lt = 0; lt < 8; ++lt) acc2[lt] = fzero;
        float mrun = -3.0e38f;
        float sp   = 0.f;

        #pragma unroll 1
        for (int a = 0; a < 4; ++a) {
            const f16* wsc = wsm + (a * 64) * L_;
            f32x4 acc[4];
            #pragma unroll
            for (int ct = 0; ct < 4; ++ct) acc[ct] = fzero;

            // region ks0: issue ks1 loads (afB), MFMA ks0 (afA)
            #pragma unroll
            for (int ct = 0; ct < 4; ++ct)
                afB[ct] = *reinterpret_cast<const f16x8*>(wsc + (ct * 16) * L_ + 32);
            #pragma unroll
            for (int ct = 0; ct < 4; ++ct)
                acc[ct] = __builtin_amdgcn_mfma_f32_16x16x32_f16(afA[ct], bf[0], acc[ct], 0, 0, 0);
            __builtin_amdgcn_sched_barrier(0);

            // region ks1: issue ks2 loads (afA), MFMA ks1 (afB)
            #pragma unroll
            for (int ct = 0; ct < 4; ++ct)
                afA[ct] = *reinterpret_cast<const f16x8*>(wsc + (ct * 16) * L_ + 64);
            #pragma unroll
            for (int ct = 0; ct < 4; ++ct)
                acc[ct] = __builtin_amdgcn_mfma_f32_16x16x32_f16(afB[ct], bf[1], acc[ct], 0, 0, 0);
            __builtin_amdgcn_sched_barrier(0);

            // region ks2: issue ks3 loads (afB), MFMA ks2 (afA)
            #pragma unroll
            for (int ct = 0; ct < 4; ++ct)
                afB[ct] = *reinterpret_cast<const f16x8*>(wsc + (ct * 16) * L_ + 96);
            #pragma unroll
            for (int ct = 0; ct < 4; ++ct)
                acc[ct] = __builtin_amdgcn_mfma_f32_16x16x32_f16(afA[ct], bf[2], acc[ct], 0, 0, 0);
            __builtin_amdgcn_sched_barrier(0);

            // region ks3: issue NEXT chunk's ks0 loads (afA; a=3 wraps to a=0
            // for the next it -- ws frags are it-invariant), MFMA ks3 (afB)
            {
                const f16* wsn = wsm + (((a + 1) & 3) * 64) * L_;
                #pragma unroll
                for (int ct = 0; ct < 4; ++ct)
                    afA[ct] = *reinterpret_cast<const f16x8*>(wsn + (ct * 16) * L_);
            }
            #pragma unroll
            for (int ct = 0; ct < 4; ++ct)
                acc[ct] = __builtin_amdgcn_mfma_f32_16x16x32_f16(afB[ct], bf[3], acc[ct], 0, 0, 0);
            __builtin_amdgcn_sched_barrier(0);

            // logits + chunk max (column-wide)
            float cmax = -3.0e38f;
            #pragma unroll
            for (int ct = 0; ct < 4; ++ct) {
                acc[ct][0] *= fac; acc[ct][1] *= fac;
                acc[ct][2] *= fac; acc[ct][3] *= fac;
                cmax = fmaxf(cmax, fmaxf(fmaxf(acc[ct][0], acc[ct][1]),
                                         fmaxf(acc[ct][2], acc[ct][3])));
            }
            cmax = fmaxf(cmax, __shfl_xor(cmax, 16));
            cmax = fmaxf(cmax, __shfl_xor(cmax, 32));
            const float mnew = fmaxf(mrun, cmax);
            const float r = __expf(mrun - mnew);
            mrun = mnew;
            sp *= r;
            #pragma unroll
            for (int lt = 0; lt < 8; ++lt) {
                acc2[lt][0] *= r; acc2[lt][1] *= r;
                acc2[lt][2] *= r; acc2[lt][3] *= r;
            }
            // exp + per-lane sum + pack
            u32 P[8];
            #pragma unroll
            for (int ct = 0; ct < 4; ++ct) {
                float p0 = __expf(acc[ct][0] - mrun);
                float p1 = __expf(acc[ct][1] - mrun);
                float p2 = __expf(acc[ct][2] - mrun);
                float p3 = __expf(acc[ct][3] - mrun);
                sp += (p0 + p1) + (p2 + p3);
                P[2 * ct]     = __builtin_bit_cast(u32, __builtin_amdgcn_cvt_pkrtz(p0, p1));
                P[2 * ct + 1] = __builtin_bit_cast(u32, __builtin_amdgcn_cvt_pkrtz(p2, p3));
            }
            __builtin_amdgcn_sched_barrier(0);
            // phase-2 chunk: acc2 += csB[:, chunk] . p_chunk
            #pragma unroll
            for (int j = 0; j < 2; ++j) {
                union { f16x8 v; u32 q[4]; } pb;
                pb.q[0] = P[4 * j + 0]; pb.q[1] = P[4 * j + 1];
                pb.q[2] = P[4 * j + 2]; pb.q[3] = P[4 * j + 3];
                const int ks2 = 2 * a + j;
                #pragma unroll
                for (int lt = 0; lt < 8; ++lt) {
                    f16x8 a2 = *reinterpret_cast<const f16x8*>(
                        csB + (lt * 16 + n) * 512 + ((64 * ks2 + 16 * g) ^ ((n & 7) << 4)));
                    acc2[lt] = __builtin_amdgcn_mfma_f32_16x16x32_f16(a2, pb.v, acc2[lt], 0, 0, 0);
                }
                __builtin_amdgcn_sched_barrier(0);   // cap in-flight csB frags at 32 regs
            }
        }

        // ---- final sum reduce + normalized store ----
        sp += __shfl_xor(sp, 16);
        sp += __shfl_xor(sp, 32);
        const float invS = 1.0f / sp;

        float* po = out + (size_t)row0 * D_ + m * L_ + 4 * g;
        #pragma unroll
        for (int lt = 0; lt < 8; ++lt) {
            f32x4 v;
            v[0] = acc2[lt][0] * invS; v[1] = acc2[lt][1] * invS;
            v[2] = acc2[lt][2] * invS; v[3] = acc2[lt][3] * invS;
            *reinterpret_cast<f32x4*>(po + 16 * lt) = v;
        }
    }
}

extern "C" void kernel_launch(void* const* d_in, const int* in_sizes, int n_in,
                              void* d_out, int out_size, void* d_ws, size_t ws_size,
                              hipStream_t stream) {
    const float* x = (const float*)d_in[0];   // [32768, 1024] f32
    const float* c = (const float*)d_in[1];   // [1024, 256]   f32
    float* out = (float*)d_out;               // [32768, 1024] f32
    f16* ws = (f16*)d_ws;                     // 512 KB: [8][256 rho][128] f16
    (void)in_sizes; (void)n_in; (void)out_size; (void)ws_size;

    pqn_prep<<<dim3(2048), dim3(128), 0, stream>>>(c, ws);
    pqn_main<<<dim3(512), dim3(512), 0, stream>>>(x, c, ws, out);
}